// Round 5
// baseline (561.124 us; speedup 1.0000x reference)
//
#include <hip/hip_runtime.h>

// Problem constants (fixed by the reference)
#define NN 50000
#define NE 800000
#define ND 16
#define ED 16
#define H  128
#define OD 4
#define SCAN_T 512
#define KP 160      // padded K: 128 h + 16 ea_agg + deg + 1 + 14 zero
#define LDA 168     // LDS row stride (shorts) to break bank conflicts
#define NBIN 64

typedef __bf16 bf16;
typedef __attribute__((ext_vector_type(8))) __bf16 bf16x8;
typedef __attribute__((ext_vector_type(4))) float f32x4;

static __device__ __forceinline__ float bf2f(unsigned short u) {
  return __builtin_bit_cast(float, (unsigned int)u << 16);
}
static __device__ __forceinline__ unsigned short f2bfu(float f) {
  return __builtin_bit_cast(unsigned short, (bf16)f);
}

// ---------------------------------------------------------------------------
// zero deg + cursor + degree-bins
// ---------------------------------------------------------------------------
__global__ __launch_bounds__(256) void zero_kernel(
    int* __restrict__ deg, int* __restrict__ cursor,
    int* __restrict__ binc, int* __restrict__ bincur) {
  int i = blockIdx.x * 256 + threadIdx.x;
  if (i < NN) { deg[i] = 0; cursor[i] = 0; }
  if (blockIdx.x == 0 && threadIdx.x < NBIN) {
    binc[threadIdx.x] = 0; bincur[threadIdx.x] = 0;
  }
}

// in-degree count, 4 edges/thread, int4 reads
__global__ __launch_bounds__(256) void degcount_kernel(
    const int* __restrict__ ei, int* __restrict__ deg) {
  int e0 = (blockIdx.x * 256 + threadIdx.x) * 4;
  if (e0 >= NE) return;   // NE % 4 == 0
  int4 d4 = *(const int4*)&ei[NE + e0];
  atomicAdd(&deg[d4.x], 1);
  atomicAdd(&deg[d4.y], 1);
  atomicAdd(&deg[d4.z], 1);
  atomicAdd(&deg[d4.w], 1);
}

// scan within tiles + degree histogram (fused)
__global__ __launch_bounds__(SCAN_T) void scan_part_kernel(
    const int* __restrict__ deg, int* __restrict__ offsets,
    int* __restrict__ tops, int* __restrict__ binc) {
  __shared__ int s[SCAN_T];
  int t = threadIdx.x;
  int i = blockIdx.x * SCAN_T + t;
  int v = (i < NN) ? deg[i] : 0;
  if (i < NN) atomicAdd(&binc[v < NBIN ? v : NBIN - 1], 1);
  s[t] = v;
  __syncthreads();
  for (int off = 1; off < SCAN_T; off <<= 1) {
    int a = (t >= off) ? s[t - off] : 0;
    __syncthreads();
    s[t] += a;
    __syncthreads();
  }
  if (i < NN) offsets[i] = s[t] - v;
  if (t == SCAN_T - 1) tops[blockIdx.x] = s[t];
}

// serial scan of tile tops + degree-bin starts (fused)
__global__ void scan_tops_kernel(int* __restrict__ tops, int ntiles,
                                 int* __restrict__ offsets,
                                 const int* __restrict__ binc,
                                 int* __restrict__ binstart) {
  if (threadIdx.x == 0) {
    int run = 0;
    for (int b = 0; b < ntiles; ++b) { int v = tops[b]; tops[b] = run; run += v; }
    offsets[NN] = NE;
    int r2 = 0;
    for (int b = 0; b < NBIN; ++b) { binstart[b] = r2; r2 += binc[b]; }
  }
}

__global__ __launch_bounds__(256) void scan_add_kernel(
    int* __restrict__ offsets, const int* __restrict__ tops) {
  int i = blockIdx.x * 256 + threadIdx.x;
  if (i < NN) offsets[i] += tops[i / SCAN_T];
}

// degree-bucketed node permutation: waves get equal-degree nodes
__global__ __launch_bounds__(256) void bin_scatter_kernel(
    const int* __restrict__ deg, const int* __restrict__ binstart,
    int* __restrict__ bincur, int* __restrict__ perm) {
  int i = blockIdx.x * 256 + threadIdx.x;
  if (i >= NN) return;
  int d = deg[i]; int b = d < NBIN ? d : NBIN - 1;
  int pos = atomicAdd(&bincur[b], 1);
  perm[binstart[b] + pos] = i;
}

// fill CSR: one nontemporal 8B store per edge (src | eid<<32)
__global__ __launch_bounds__(256) void csr_fill_kernel(
    const int* __restrict__ ei, const int* __restrict__ offsets,
    int* __restrict__ cursor, long long* __restrict__ csr) {
  int e0 = (blockIdx.x * 256 + threadIdx.x) * 4;
  if (e0 >= NE) return;
  int4 s4 = *(const int4*)&ei[e0];
  int4 d4 = *(const int4*)&ei[NE + e0];
#pragma unroll
  for (int j = 0; j < 4; ++j) {
    int src = (&s4.x)[j];
    int dst = (&d4.x)[j];
    int pos = atomicAdd(&cursor[dst], 1);
    long long pk = (long long)((unsigned long long)(unsigned)(e0 + j) << 32) |
                   (unsigned)src;
    __builtin_nontemporal_store(pk, &csr[offsets[dst] + pos]);
  }
}

// ---------------------------------------------------------------------------
// A[:,128:160] = [ sum_{e->i} ea[e] (16) | deg | 1.0 | zeros(14) ]  (bf16)
// 16 lanes per node, degree-sorted order
// ---------------------------------------------------------------------------
__global__ __launch_bounds__(256) void edge_static_kernel(
    const int* __restrict__ offsets, const long long* __restrict__ csr,
    const float* __restrict__ ea, const int* __restrict__ perm,
    bf16* __restrict__ A) {
  int t = threadIdx.x;
  int node = perm[blockIdx.x * 16 + (t >> 4)];   // NN/16 exact
  int k = t & 15;
  int s = offsets[node], e = offsets[node + 1];
  const int* ci = (const int*)csr;
  float acc = 0.f;
  for (int p = s; p < e; ++p) {
    int eid = ci[2 * p + 1];
    acc += ea[(size_t)eid * ED + k];
  }
  unsigned short* Au = (unsigned short*)A;
  Au[(size_t)node * KP + 128 + k] = f2bfu(acc);
  float v2 = (k == 0) ? (float)(e - s) : (k == 1 ? 1.0f : 0.0f);
  Au[(size_t)node * KP + 144 + k] = f2bfu(v2);
}

// ---------------------------------------------------------------------------
// Pack W col-major: Wp[b][c][k] = W[b][k][c]
// ---------------------------------------------------------------------------
__global__ __launch_bounds__(256) void pack_w_kernel(
    const float* __restrict__ msg_w, const float* __restrict__ root_w,
    const float* __restrict__ root_b, const float* __restrict__ msg_b,
    bf16* __restrict__ Wp) {
  int idx = blockIdx.x * 256 + threadIdx.x;   // 3*256*160 exact
  int b = idx / (256 * KP);
  int r = idx % (256 * KP);
  int c = r / KP, k = r % KP;
  float v = 0.f;
  if (c < 128) {
    if (k < 128) v = msg_w[((size_t)b * 144 + k) * 128 + c];
  } else {
    int cc = c - 128;
    if (k < 128)       v = root_w[((size_t)b * 128 + k) * 128 + cc];
    else if (k < 144)  v = msg_w[((size_t)b * 144 + k) * 128 + cc];
    else if (k == 144) v = msg_b[(size_t)b * 128 + cc];
    else if (k == 145) v = root_b[(size_t)b * 128 + cc];
  }
  Wp[idx] = (bf16)v;
}

// ---------------------------------------------------------------------------
// lift: A[:,0:128] = bf16(x @ lift_w + lift_b)
// ---------------------------------------------------------------------------
__global__ __launch_bounds__(256) void lift_kernel(
    const float* __restrict__ x, const float* __restrict__ lw,
    const float* __restrict__ lb, bf16* __restrict__ A) {
  int idx = blockIdx.x * 256 + threadIdx.x;   // NN*128 exact
  int n = idx >> 7, k = idx & 127;
  float acc = lb[k];
  const float* xr = x + (size_t)n * ND;
#pragma unroll
  for (int j = 0; j < ND; ++j) acc = fmaf(xr[j], lw[j * H + k], acc);
  A[(size_t)n * KP + k] = (bf16)acc;
}

// ---------------------------------------------------------------------------
// MFMA GEMM: [NN x 160] @ [160 x 256] -> Hw (bf16) | base (f32, +identity)
// one 64-node tile per block (782 blocks exact)
// ---------------------------------------------------------------------------
__global__ __launch_bounds__(256, 2) void gemm_mfma_kernel(
    const bf16* __restrict__ A, const bf16* __restrict__ Wp,
    bf16* __restrict__ Hw, float* __restrict__ base) {
  __shared__ bf16 as[64 * LDA];
  int t = threadIdx.x;
  int lane = t & 63;
  int wv = t >> 6;
  int l15 = lane & 15, g = lane >> 4;
  int c0w = wv * 64;

  bf16x8 bq[5][4];
#pragma unroll
  for (int kk = 0; kk < 5; ++kk)
#pragma unroll
    for (int ni = 0; ni < 4; ++ni)
      bq[kk][ni] = *(const bf16x8*)(Wp + (size_t)(c0w + ni * 16 + l15) * KP + kk * 32 + g * 8);

  int m0 = blockIdx.x * 64;
#pragma unroll
  for (int i = 0; i < 5; ++i) {
    int idx = i * 256 + t;
    int r = idx / 20, seg = idx % 20;
    int node = m0 + r;
    float4 v = make_float4(0.f, 0.f, 0.f, 0.f);
    if (node < NN) v = *(const float4*)(A + (size_t)node * KP + seg * 8);
    *(float4*)(as + r * LDA + seg * 8) = v;
  }
  __syncthreads();

  f32x4 acc[4][4];
#pragma unroll
  for (int mi = 0; mi < 4; ++mi)
#pragma unroll
    for (int ni = 0; ni < 4; ++ni)
      acc[mi][ni] = (f32x4){0.f, 0.f, 0.f, 0.f};

#pragma unroll
  for (int kk = 0; kk < 5; ++kk) {
    bf16x8 af[4];
#pragma unroll
    for (int mi = 0; mi < 4; ++mi)
      af[mi] = *(const bf16x8*)(as + (mi * 16 + l15) * LDA + kk * 32 + g * 8);
#pragma unroll
    for (int mi = 0; mi < 4; ++mi)
#pragma unroll
      for (int ni = 0; ni < 4; ++ni)
        acc[mi][ni] = __builtin_amdgcn_mfma_f32_16x16x32_bf16(
            af[mi], bq[kk][ni], acc[mi][ni], 0, 0, 0);
  }

#pragma unroll
  for (int mi = 0; mi < 4; ++mi) {
#pragma unroll
    for (int ni = 0; ni < 4; ++ni) {
#pragma unroll
      for (int i = 0; i < 4; ++i) {
        int rloc = mi * 16 + g * 4 + i;
        int row = m0 + rloc;
        int col = c0w + ni * 16 + l15;
        if (row < NN) {
          float v = acc[mi][ni][i];
          if (wv < 2) {
            Hw[(size_t)row * H + col] = (bf16)v;
          } else {
            int cc = col - 128;
            v += bf2f(__builtin_bit_cast(unsigned short, as[rloc * LDA + cc]));
            base[(size_t)row * H + cc] = v;
          }
        }
      }
    }
  }
}

// ---------------------------------------------------------------------------
// h_next = act( base + sum_{e->i} Hw[src[e]] ) -> A[:,0:128] (bf16)
// 16 lanes x 16B per node; degree-sorted node order (uniform waves)
// ---------------------------------------------------------------------------
__global__ __launch_bounds__(256) void gather_update_kernel(
    const int* __restrict__ offsets, const long long* __restrict__ csr,
    const bf16* __restrict__ Hw, const float* __restrict__ base,
    const int* __restrict__ perm, bf16* __restrict__ A, int act) {
  int t = threadIdx.x;
  int node = perm[blockIdx.x * 16 + (t >> 4)];   // NN/16 exact
  int li = t & 15;
  int k8 = li * 8;
  int s = offsets[node], e = offsets[node + 1];
  const int* ci = (const int*)csr;
  const unsigned short* Hu = (const unsigned short*)Hw;

  float acc[8];
  {
    float4 b0 = *(const float4*)&base[(size_t)node * H + k8];
    float4 b1 = *(const float4*)&base[(size_t)node * H + k8 + 4];
    acc[0] = b0.x; acc[1] = b0.y; acc[2] = b0.z; acc[3] = b0.w;
    acc[4] = b1.x; acc[5] = b1.y; acc[6] = b1.z; acc[7] = b1.w;
  }

  int p = s;
  for (; p + 2 <= e; p += 2) {
    int s0 = ci[2 * p];
    int s1 = ci[2 * p + 2];
    uint4 v0 = *(const uint4*)&Hu[(size_t)s0 * H + k8];
    uint4 v1 = *(const uint4*)&Hu[(size_t)s1 * H + k8];
    acc[0] += bf2f((unsigned short)(v0.x & 0xffff)) + bf2f((unsigned short)(v1.x & 0xffff));
    acc[1] += bf2f((unsigned short)(v0.x >> 16))    + bf2f((unsigned short)(v1.x >> 16));
    acc[2] += bf2f((unsigned short)(v0.y & 0xffff)) + bf2f((unsigned short)(v1.y & 0xffff));
    acc[3] += bf2f((unsigned short)(v0.y >> 16))    + bf2f((unsigned short)(v1.y >> 16));
    acc[4] += bf2f((unsigned short)(v0.z & 0xffff)) + bf2f((unsigned short)(v1.z & 0xffff));
    acc[5] += bf2f((unsigned short)(v0.z >> 16))    + bf2f((unsigned short)(v1.z >> 16));
    acc[6] += bf2f((unsigned short)(v0.w & 0xffff)) + bf2f((unsigned short)(v1.w & 0xffff));
    acc[7] += bf2f((unsigned short)(v0.w >> 16))    + bf2f((unsigned short)(v1.w >> 16));
  }
  if (p < e) {
    int s0 = ci[2 * p];
    uint4 v0 = *(const uint4*)&Hu[(size_t)s0 * H + k8];
    acc[0] += bf2f((unsigned short)(v0.x & 0xffff));
    acc[1] += bf2f((unsigned short)(v0.x >> 16));
    acc[2] += bf2f((unsigned short)(v0.y & 0xffff));
    acc[3] += bf2f((unsigned short)(v0.y >> 16));
    acc[4] += bf2f((unsigned short)(v0.z & 0xffff));
    acc[5] += bf2f((unsigned short)(v0.z >> 16));
    acc[6] += bf2f((unsigned short)(v0.w & 0xffff));
    acc[7] += bf2f((unsigned short)(v0.w >> 16));
  }

  if (act) {
#pragma unroll
    for (int j = 0; j < 8; ++j) {
      float v = acc[j];
      float u = 0.7978845608028654f * (v + 0.044715f * v * v * v);
      acc[j] = 0.5f * v * (1.f + tanhf(u));
    }
  }

  uint4 o;
  o.x = (unsigned int)f2bfu(acc[0]) | ((unsigned int)f2bfu(acc[1]) << 16);
  o.y = (unsigned int)f2bfu(acc[2]) | ((unsigned int)f2bfu(acc[3]) << 16);
  o.z = (unsigned int)f2bfu(acc[4]) | ((unsigned int)f2bfu(acc[5]) << 16);
  o.w = (unsigned int)f2bfu(acc[6]) | ((unsigned int)f2bfu(acc[7]) << 16);
  *(uint4*)&((unsigned short*)A)[(size_t)node * KP + k8] = o;
}

// ---------------------------------------------------------------------------
// out = h @ proj_w + proj_b
// ---------------------------------------------------------------------------
__global__ __launch_bounds__(256) void proj_kernel(
    const bf16* __restrict__ A, const float* __restrict__ pw,
    const float* __restrict__ pb, float* __restrict__ out) {
  int idx = blockIdx.x * 256 + threadIdx.x;
  if (idx >= NN * OD) return;
  int n = idx >> 2, o = idx & 3;
  float acc = pb[o];
  const unsigned short* hr = (const unsigned short*)(A + (size_t)n * KP);
#pragma unroll
  for (int j = 0; j < H; ++j) acc = fmaf(bf2f(hr[j]), pw[j * OD + o], acc);
  out[idx] = acc;
}

extern "C" void kernel_launch(void* const* d_in, const int* in_sizes, int n_in,
                              void* d_out, int out_size, void* d_ws, size_t ws_size,
                              hipStream_t stream) {
  const float* x       = (const float*)d_in[0];
  const int*   ei      = (const int*)d_in[1];
  const float* ea      = (const float*)d_in[2];
  const float* lift_w  = (const float*)d_in[3];
  const float* lift_b  = (const float*)d_in[4];
  const float* root_w  = (const float*)d_in[5];
  const float* root_b  = (const float*)d_in[6];
  const float* msg_w   = (const float*)d_in[7];
  const float* msg_b   = (const float*)d_in[8];
  const float* proj_w  = (const float*)d_in[9];
  const float* proj_b  = (const float*)d_in[10];
  float* out = (float*)d_out;

  char* w = (char*)d_ws;
  bf16*  A      = (bf16*)w;              w += (size_t)NN * KP * 2;       // 16.0 MB
  bf16*  Hw     = (bf16*)w;              w += (size_t)NN * H * 2;        // 12.8 MB
  float* base   = (float*)w;             w += (size_t)NN * H * 4;        // 25.6 MB
  bf16*  Wp     = (bf16*)w;              w += (size_t)3 * 256 * KP * 2;  // 0.25 MB
  long long* csr = (long long*)w;        w += (size_t)NE * 8;            // 6.4 MB
  int*   deg     = (int*)w;              w += (size_t)NN * 4;
  int*   cursor  = (int*)w;              w += (size_t)NN * 4;
  int*   offsets = (int*)w;              w += (size_t)(NN + 16) * 4;
  int*   tops    = (int*)w;              w += 128 * 4;
  int*   perm    = (int*)w;              w += (size_t)NN * 4;
  int*   binc    = (int*)w;              w += NBIN * 4;
  int*   binstart= (int*)w;              w += NBIN * 4;
  int*   bincur  = (int*)w;

  const int ntiles = (NN + SCAN_T - 1) / SCAN_T;  // 98

  zero_kernel<<<(NN + 255) / 256, 256, 0, stream>>>(deg, cursor, binc, bincur);
  degcount_kernel<<<(NE / 4 + 255) / 256, 256, 0, stream>>>(ei, deg);
  scan_part_kernel<<<ntiles, SCAN_T, 0, stream>>>(deg, offsets, tops, binc);
  scan_tops_kernel<<<1, 64, 0, stream>>>(tops, ntiles, offsets, binc, binstart);
  scan_add_kernel<<<(NN + 255) / 256, 256, 0, stream>>>(offsets, tops);
  bin_scatter_kernel<<<(NN + 255) / 256, 256, 0, stream>>>(deg, binstart, bincur, perm);
  csr_fill_kernel<<<(NE / 4 + 255) / 256, 256, 0, stream>>>(ei, offsets, cursor, csr);

  edge_static_kernel<<<NN / 16, 256, 0, stream>>>(offsets, csr, ea, perm, A);
  pack_w_kernel<<<(3 * 256 * KP) / 256, 256, 0, stream>>>(msg_w, root_w, root_b, msg_b, Wp);
  lift_kernel<<<(NN * H) / 256, 256, 0, stream>>>(x, lift_w, lift_b, A);

  for (int b = 0; b < 3; ++b) {
    gemm_mfma_kernel<<<(NN + 63) / 64, 256, 0, stream>>>(
        A, Wp + (size_t)b * 256 * KP, Hw, base);
    gather_update_kernel<<<NN / 16, 256, 0, stream>>>(
        offsets, csr, Hw, base, perm, A, b < 2 ? 1 : 0);
  }

  proj_kernel<<<(NN * OD + 255) / 256, 256, 0, stream>>>(A, proj_w, proj_b, out);
}

// Round 6
// 329.268 us; speedup vs baseline: 1.7042x; 1.7042x over previous
//
#include <hip/hip_runtime.h>

// Problem constants (fixed by the reference)
#define NN 50000
#define NE 800000
#define ND 16
#define ED 16
#define H  128
#define OD 4
#define SCAN_T 512
#define KP 160      // padded K: 128 h + 16 ea_agg + deg + 1 + 14 zero
#define LDA 168     // LDS row stride (shorts) to break bank conflicts

typedef __bf16 bf16;
typedef __attribute__((ext_vector_type(8))) __bf16 bf16x8;
typedef __attribute__((ext_vector_type(4))) float f32x4;

static __device__ __forceinline__ float bf2f(unsigned short u) {
  return __builtin_bit_cast(float, (unsigned int)u << 16);
}
static __device__ __forceinline__ unsigned short f2bfu(float f) {
  return __builtin_bit_cast(unsigned short, (bf16)f);
}

// ---------------------------------------------------------------------------
// CSR build
// ---------------------------------------------------------------------------
__global__ __launch_bounds__(256) void zero_kernel(int* __restrict__ deg,
                                                   int* __restrict__ cursor) {
  int i = blockIdx.x * 256 + threadIdx.x;
  if (i < NN) { deg[i] = 0; cursor[i] = 0; }
}

// in-degree count, 4 edges/thread, int4 reads
__global__ __launch_bounds__(256) void degcount_kernel(
    const int* __restrict__ ei, int* __restrict__ deg) {
  int e0 = (blockIdx.x * 256 + threadIdx.x) * 4;
  if (e0 >= NE) return;   // NE % 4 == 0
  int4 d4 = *(const int4*)&ei[NE + e0];
  atomicAdd(&deg[d4.x], 1);
  atomicAdd(&deg[d4.y], 1);
  atomicAdd(&deg[d4.z], 1);
  atomicAdd(&deg[d4.w], 1);
}

__global__ __launch_bounds__(SCAN_T) void scan_part_kernel(
    const int* __restrict__ deg, int* __restrict__ offsets,
    int* __restrict__ tops) {
  __shared__ int s[SCAN_T];
  int t = threadIdx.x;
  int i = blockIdx.x * SCAN_T + t;
  int v = (i < NN) ? deg[i] : 0;
  s[t] = v;
  __syncthreads();
  for (int off = 1; off < SCAN_T; off <<= 1) {
    int a = (t >= off) ? s[t - off] : 0;
    __syncthreads();
    s[t] += a;
    __syncthreads();
  }
  if (i < NN) offsets[i] = s[t] - v;
  if (t == SCAN_T - 1) tops[blockIdx.x] = s[t];
}

__global__ void scan_tops_kernel(int* __restrict__ tops, int ntiles,
                                 int* __restrict__ offsets) {
  if (threadIdx.x == 0) {
    int run = 0;
    for (int b = 0; b < ntiles; ++b) { int v = tops[b]; tops[b] = run; run += v; }
    offsets[NN] = NE;
  }
}

__global__ __launch_bounds__(256) void scan_add_kernel(
    int* __restrict__ offsets, const int* __restrict__ tops) {
  int i = blockIdx.x * 256 + threadIdx.x;
  if (i < NN) offsets[i] += tops[i / SCAN_T];
}

// ---------------------------------------------------------------------------
// fill CSR, XCD-write-partitioned: block handles partition (blockIdx%8) of
// chunk (blockIdx/8). Every edge is claimed by exactly one partition
// ((dst*8)/NN), so coverage is exact regardless of block->XCD mapping.
// Under round-robin dispatch, all writes + cursor atomics for a given dst
// come from ONE XCD -> L2 write coalescing, no cross-XCD partial-line amp.
// ---------------------------------------------------------------------------
__global__ __launch_bounds__(256) void csr_fill_kernel(
    const int* __restrict__ ei, const int* __restrict__ offsets,
    int* __restrict__ cursor, long long* __restrict__ csr) {
  int part = blockIdx.x & 7;
  int e0 = (blockIdx.x >> 3) * 1024 + threadIdx.x * 4;
  if (e0 >= NE) return;
  int4 s4 = *(const int4*)&ei[e0];
  int4 d4 = *(const int4*)&ei[NE + e0];
#pragma unroll
  for (int j = 0; j < 4; ++j) {
    int src = (&s4.x)[j];
    int dst = (&d4.x)[j];
    if ((int)(((long long)dst * 8) / NN) == part) {
      int pos = atomicAdd(&cursor[dst], 1);
      long long pk = (long long)((unsigned long long)(unsigned)(e0 + j) << 32) |
                     (unsigned)src;
      csr[offsets[dst] + pos] = pk;
    }
  }
}

// ---------------------------------------------------------------------------
// A[:,128:160] = [ sum_{e->i} ea[e] (16) | deg | 1.0 | zeros(14) ]  (bf16)
// ---------------------------------------------------------------------------
__global__ __launch_bounds__(256) void edge_static_kernel(
    const int* __restrict__ offsets, const long long* __restrict__ csr,
    const float* __restrict__ ea, bf16* __restrict__ A) {
  int t = threadIdx.x;
  int node = blockIdx.x * 16 + (t >> 4);   // NN/16 exact
  int k = t & 15;
  int s = offsets[node], e = offsets[node + 1];
  const int* ci = (const int*)csr;
  float acc = 0.f;
  for (int p = s; p < e; ++p) {
    int eid = ci[2 * p + 1];
    acc += ea[(size_t)eid * ED + k];
  }
  unsigned short* Au = (unsigned short*)A;
  Au[(size_t)node * KP + 128 + k] = f2bfu(acc);
  float v2 = (k == 0) ? (float)(e - s) : (k == 1 ? 1.0f : 0.0f);
  Au[(size_t)node * KP + 144 + k] = f2bfu(v2);
}

// ---------------------------------------------------------------------------
// Pack W col-major: Wp[b][c][k] = W[b][k][c]
// ---------------------------------------------------------------------------
__global__ __launch_bounds__(256) void pack_w_kernel(
    const float* __restrict__ msg_w, const float* __restrict__ root_w,
    const float* __restrict__ root_b, const float* __restrict__ msg_b,
    bf16* __restrict__ Wp) {
  int idx = blockIdx.x * 256 + threadIdx.x;   // 3*256*160 exact
  int b = idx / (256 * KP);
  int r = idx % (256 * KP);
  int c = r / KP, k = r % KP;
  float v = 0.f;
  if (c < 128) {
    if (k < 128) v = msg_w[((size_t)b * 144 + k) * 128 + c];
  } else {
    int cc = c - 128;
    if (k < 128)       v = root_w[((size_t)b * 128 + k) * 128 + cc];
    else if (k < 144)  v = msg_w[((size_t)b * 144 + k) * 128 + cc];
    else if (k == 144) v = msg_b[(size_t)b * 128 + cc];
    else if (k == 145) v = root_b[(size_t)b * 128 + cc];
  }
  Wp[idx] = (bf16)v;
}

// ---------------------------------------------------------------------------
// lift: A[:,0:128] = bf16(x @ lift_w + lift_b)
// ---------------------------------------------------------------------------
__global__ __launch_bounds__(256) void lift_kernel(
    const float* __restrict__ x, const float* __restrict__ lw,
    const float* __restrict__ lb, bf16* __restrict__ A) {
  int idx = blockIdx.x * 256 + threadIdx.x;   // NN*128 exact
  int n = idx >> 7, k = idx & 127;
  float acc = lb[k];
  const float* xr = x + (size_t)n * ND;
#pragma unroll
  for (int j = 0; j < ND; ++j) acc = fmaf(xr[j], lw[j * H + k], acc);
  A[(size_t)n * KP + k] = (bf16)acc;
}

// ---------------------------------------------------------------------------
// MFMA GEMM: [NN x 160] @ [160 x 256] -> Hw (bf16) | base (f32, +identity)
// ---------------------------------------------------------------------------
__global__ __launch_bounds__(256, 2) void gemm_mfma_kernel(
    const bf16* __restrict__ A, const bf16* __restrict__ Wp,
    bf16* __restrict__ Hw, float* __restrict__ base) {
  __shared__ bf16 as[64 * LDA];
  int t = threadIdx.x;
  int lane = t & 63;
  int wv = t >> 6;
  int l15 = lane & 15, g = lane >> 4;
  int c0w = wv * 64;

  bf16x8 bq[5][4];
#pragma unroll
  for (int kk = 0; kk < 5; ++kk)
#pragma unroll
    for (int ni = 0; ni < 4; ++ni)
      bq[kk][ni] = *(const bf16x8*)(Wp + (size_t)(c0w + ni * 16 + l15) * KP + kk * 32 + g * 8);

  int m0 = blockIdx.x * 64;
#pragma unroll
  for (int i = 0; i < 5; ++i) {
    int idx = i * 256 + t;
    int r = idx / 20, seg = idx % 20;
    int node = m0 + r;
    float4 v = make_float4(0.f, 0.f, 0.f, 0.f);
    if (node < NN) v = *(const float4*)(A + (size_t)node * KP + seg * 8);
    *(float4*)(as + r * LDA + seg * 8) = v;
  }
  __syncthreads();

  f32x4 acc[4][4];
#pragma unroll
  for (int mi = 0; mi < 4; ++mi)
#pragma unroll
    for (int ni = 0; ni < 4; ++ni)
      acc[mi][ni] = (f32x4){0.f, 0.f, 0.f, 0.f};

#pragma unroll
  for (int kk = 0; kk < 5; ++kk) {
    bf16x8 af[4];
#pragma unroll
    for (int mi = 0; mi < 4; ++mi)
      af[mi] = *(const bf16x8*)(as + (mi * 16 + l15) * LDA + kk * 32 + g * 8);
#pragma unroll
    for (int mi = 0; mi < 4; ++mi)
#pragma unroll
      for (int ni = 0; ni < 4; ++ni)
        acc[mi][ni] = __builtin_amdgcn_mfma_f32_16x16x32_bf16(
            af[mi], bq[kk][ni], acc[mi][ni], 0, 0, 0);
  }

#pragma unroll
  for (int mi = 0; mi < 4; ++mi) {
#pragma unroll
    for (int ni = 0; ni < 4; ++ni) {
#pragma unroll
      for (int i = 0; i < 4; ++i) {
        int rloc = mi * 16 + g * 4 + i;
        int row = m0 + rloc;
        int col = c0w + ni * 16 + l15;
        if (row < NN) {
          float v = acc[mi][ni][i];
          if (wv < 2) {
            Hw[(size_t)row * H + col] = (bf16)v;
          } else {
            int cc = col - 128;
            v += bf2f(__builtin_bit_cast(unsigned short, as[rloc * LDA + cc]));
            base[(size_t)row * H + cc] = v;
          }
        }
      }
    }
  }
}

// ---------------------------------------------------------------------------
// h_next = act( base + sum_{e->i} Hw[src[e]] )
//   act==1: write bf16 h into A[:,0:128]
//   act==0 (last block): fuse projection, write out[node][0:4], skip A write
// 16 lanes x 16B per node; 16 nodes per 256-thread block; unroll-4
// ---------------------------------------------------------------------------
__global__ __launch_bounds__(256) void gather_update_kernel(
    const int* __restrict__ offsets, const long long* __restrict__ csr,
    const bf16* __restrict__ Hw, const float* __restrict__ base,
    bf16* __restrict__ A, const float* __restrict__ pw,
    const float* __restrict__ pb, float* __restrict__ out, int act) {
  int t = threadIdx.x;
  int node = blockIdx.x * 16 + (t >> 4);   // NN/16 exact
  int li = t & 15;
  int k8 = li * 8;
  int s = offsets[node], e = offsets[node + 1];
  const int* ci = (const int*)csr;
  const unsigned short* Hu = (const unsigned short*)Hw;

  float acc[8];
  {
    float4 b0 = *(const float4*)&base[(size_t)node * H + k8];
    float4 b1 = *(const float4*)&base[(size_t)node * H + k8 + 4];
    acc[0] = b0.x; acc[1] = b0.y; acc[2] = b0.z; acc[3] = b0.w;
    acc[4] = b1.x; acc[5] = b1.y; acc[6] = b1.z; acc[7] = b1.w;
  }

  int p = s;
  for (; p + 4 <= e; p += 4) {
    int s0 = ci[2 * p];
    int s1 = ci[2 * p + 2];
    int s2 = ci[2 * p + 4];
    int s3 = ci[2 * p + 6];
    uint4 v0 = *(const uint4*)&Hu[(size_t)s0 * H + k8];
    uint4 v1 = *(const uint4*)&Hu[(size_t)s1 * H + k8];
    uint4 v2 = *(const uint4*)&Hu[(size_t)s2 * H + k8];
    uint4 v3 = *(const uint4*)&Hu[(size_t)s3 * H + k8];
#pragma unroll
    for (int j = 0; j < 4; ++j) {
      unsigned int w0 = (&v0.x)[j], w1 = (&v1.x)[j], w2 = (&v2.x)[j], w3 = (&v3.x)[j];
      acc[2 * j]     += (bf2f((unsigned short)(w0 & 0xffff)) + bf2f((unsigned short)(w1 & 0xffff)))
                      + (bf2f((unsigned short)(w2 & 0xffff)) + bf2f((unsigned short)(w3 & 0xffff)));
      acc[2 * j + 1] += (bf2f((unsigned short)(w0 >> 16)) + bf2f((unsigned short)(w1 >> 16)))
                      + (bf2f((unsigned short)(w2 >> 16)) + bf2f((unsigned short)(w3 >> 16)));
    }
  }
  for (; p < e; ++p) {
    int s0 = ci[2 * p];
    uint4 v0 = *(const uint4*)&Hu[(size_t)s0 * H + k8];
#pragma unroll
    for (int j = 0; j < 4; ++j) {
      unsigned int w0 = (&v0.x)[j];
      acc[2 * j]     += bf2f((unsigned short)(w0 & 0xffff));
      acc[2 * j + 1] += bf2f((unsigned short)(w0 >> 16));
    }
  }

  if (act) {
#pragma unroll
    for (int j = 0; j < 8; ++j) {
      float v = acc[j];
      float u = 0.7978845608028654f * (v + 0.044715f * v * v * v);
      acc[j] = 0.5f * v * (1.f + tanhf(u));
    }
    uint4 o;
    o.x = (unsigned int)f2bfu(acc[0]) | ((unsigned int)f2bfu(acc[1]) << 16);
    o.y = (unsigned int)f2bfu(acc[2]) | ((unsigned int)f2bfu(acc[3]) << 16);
    o.z = (unsigned int)f2bfu(acc[4]) | ((unsigned int)f2bfu(acc[5]) << 16);
    o.w = (unsigned int)f2bfu(acc[6]) | ((unsigned int)f2bfu(acc[7]) << 16);
    *(uint4*)&((unsigned short*)A)[(size_t)node * KP + k8] = o;
  } else {
    // fused projection: this lane covers h cols [k8, k8+8)
    float o0 = 0.f, o1 = 0.f, o2 = 0.f, o3 = 0.f;
#pragma unroll
    for (int j = 0; j < 8; ++j) {
      float hv = acc[j];
      const float* pr = pw + (size_t)(k8 + j) * OD;
      o0 = fmaf(hv, pr[0], o0);
      o1 = fmaf(hv, pr[1], o1);
      o2 = fmaf(hv, pr[2], o2);
      o3 = fmaf(hv, pr[3], o3);
    }
    // reduce across the 16 lanes of this node's group
#pragma unroll
    for (int m = 8; m >= 1; m >>= 1) {
      o0 += __shfl_xor(o0, m, 16);
      o1 += __shfl_xor(o1, m, 16);
      o2 += __shfl_xor(o2, m, 16);
      o3 += __shfl_xor(o3, m, 16);
    }
    if (li == 0) {
      float4 ov = make_float4(o0 + pb[0], o1 + pb[1], o2 + pb[2], o3 + pb[3]);
      *(float4*)&out[(size_t)node * OD] = ov;
    }
  }
}

extern "C" void kernel_launch(void* const* d_in, const int* in_sizes, int n_in,
                              void* d_out, int out_size, void* d_ws, size_t ws_size,
                              hipStream_t stream) {
  const float* x       = (const float*)d_in[0];
  const int*   ei      = (const int*)d_in[1];
  const float* ea      = (const float*)d_in[2];
  const float* lift_w  = (const float*)d_in[3];
  const float* lift_b  = (const float*)d_in[4];
  const float* root_w  = (const float*)d_in[5];
  const float* root_b  = (const float*)d_in[6];
  const float* msg_w   = (const float*)d_in[7];
  const float* msg_b   = (const float*)d_in[8];
  const float* proj_w  = (const float*)d_in[9];
  const float* proj_b  = (const float*)d_in[10];
  float* out = (float*)d_out;

  char* w = (char*)d_ws;
  bf16*  A      = (bf16*)w;              w += (size_t)NN * KP * 2;       // 16.0 MB
  bf16*  Hw     = (bf16*)w;              w += (size_t)NN * H * 2;        // 12.8 MB
  float* base   = (float*)w;             w += (size_t)NN * H * 4;        // 25.6 MB
  bf16*  Wp     = (bf16*)w;              w += (size_t)3 * 256 * KP * 2;  // 0.25 MB
  long long* csr = (long long*)w;        w += (size_t)NE * 8;            // 6.4 MB
  int*   deg     = (int*)w;              w += (size_t)NN * 4;
  int*   cursor  = (int*)w;              w += (size_t)NN * 4;
  int*   offsets = (int*)w;              w += (size_t)(NN + 16) * 4;
  int*   tops    = (int*)w;

  const int ntiles = (NN + SCAN_T - 1) / SCAN_T;  // 98

  zero_kernel<<<(NN + 255) / 256, 256, 0, stream>>>(deg, cursor);
  degcount_kernel<<<(NE / 4 + 255) / 256, 256, 0, stream>>>(ei, deg);
  scan_part_kernel<<<ntiles, SCAN_T, 0, stream>>>(deg, offsets, tops);
  scan_tops_kernel<<<1, 64, 0, stream>>>(tops, ntiles, offsets);
  scan_add_kernel<<<(NN + 255) / 256, 256, 0, stream>>>(offsets, tops);
  csr_fill_kernel<<<8 * ((NE + 1023) / 1024), 256, 0, stream>>>(ei, offsets, cursor, csr);

  edge_static_kernel<<<NN / 16, 256, 0, stream>>>(offsets, csr, ea, A);
  pack_w_kernel<<<(3 * 256 * KP) / 256, 256, 0, stream>>>(msg_w, root_w, root_b, msg_b, Wp);
  lift_kernel<<<(NN * H) / 256, 256, 0, stream>>>(x, lift_w, lift_b, A);

  for (int b = 0; b < 3; ++b) {
    gemm_mfma_kernel<<<(NN + 63) / 64, 256, 0, stream>>>(
        A, Wp + (size_t)b * 256 * KP, Hw, base);
    gather_update_kernel<<<NN / 16, 256, 0, stream>>>(
        offsets, csr, Hw, base, A, proj_w, proj_b, out, b < 2 ? 1 : 0);
  }
}

// Round 7
// 311.225 us; speedup vs baseline: 1.8030x; 1.0580x over previous
//
#include <hip/hip_runtime.h>

// Problem constants (fixed by the reference)
#define NN 50000
#define NE 800000
#define ND 16
#define ED 16
#define H  128
#define OD 4
#define SCAN_T 512
#define KP 160      // padded K: 128 h + 16 ea_agg + deg + 1 + 14 zero
#define LDA 168     // LDS row stride (shorts) to break bank conflicts

typedef __bf16 bf16;
typedef __attribute__((ext_vector_type(8))) __bf16 bf16x8;
typedef __attribute__((ext_vector_type(4))) float f32x4;

static __device__ __forceinline__ float bf2f(unsigned short u) {
  return __builtin_bit_cast(float, (unsigned int)u << 16);
}
static __device__ __forceinline__ unsigned short f2bfu(float f) {
  return __builtin_bit_cast(unsigned short, (bf16)f);
}
static __device__ __forceinline__ unsigned int pk2(float a, float b) {
  return (unsigned int)f2bfu(a) | ((unsigned int)f2bfu(b) << 16);
}

// ---------------------------------------------------------------------------
// CSR build
// ---------------------------------------------------------------------------
__global__ __launch_bounds__(256) void zero_kernel(int* __restrict__ deg,
                                                   int* __restrict__ cursor) {
  int i = blockIdx.x * 256 + threadIdx.x;
  if (i < NN) { deg[i] = 0; cursor[i] = 0; }
}

// in-degree count, 4 edges/thread, int4 reads
__global__ __launch_bounds__(256) void degcount_kernel(
    const int* __restrict__ ei, int* __restrict__ deg) {
  int e0 = (blockIdx.x * 256 + threadIdx.x) * 4;
  if (e0 >= NE) return;   // NE % 4 == 0
  int4 d4 = *(const int4*)&ei[NE + e0];
  atomicAdd(&deg[d4.x], 1);
  atomicAdd(&deg[d4.y], 1);
  atomicAdd(&deg[d4.z], 1);
  atomicAdd(&deg[d4.w], 1);
}

__global__ __launch_bounds__(SCAN_T) void scan_part_kernel(
    const int* __restrict__ deg, int* __restrict__ offsets,
    int* __restrict__ tops) {
  __shared__ int s[SCAN_T];
  int t = threadIdx.x;
  int i = blockIdx.x * SCAN_T + t;
  int v = (i < NN) ? deg[i] : 0;
  s[t] = v;
  __syncthreads();
  for (int off = 1; off < SCAN_T; off <<= 1) {
    int a = (t >= off) ? s[t - off] : 0;
    __syncthreads();
    s[t] += a;
    __syncthreads();
  }
  if (i < NN) offsets[i] = s[t] - v;
  if (t == SCAN_T - 1) tops[blockIdx.x] = s[t];
}

__global__ void scan_tops_kernel(int* __restrict__ tops, int ntiles,
                                 int* __restrict__ offsets) {
  if (threadIdx.x == 0) {
    int run = 0;
    for (int b = 0; b < ntiles; ++b) { int v = tops[b]; tops[b] = run; run += v; }
    offsets[NN] = NE;
  }
}

__global__ __launch_bounds__(256) void scan_add_kernel(
    int* __restrict__ offsets, const int* __restrict__ tops) {
  int i = blockIdx.x * 256 + threadIdx.x;
  if (i < NN) offsets[i] += tops[i / SCAN_T];
}

// ---------------------------------------------------------------------------
// fill CSR, XCD-write-partitioned (partition = (dst*8)/NN, block blockIdx%8).
// ALSO scatters ea[e] -> ea_perm[slot] as bf16 (32 B full row per edge), so
// the downstream ea reduction is a pure streaming read in CSR order.
// Each ea line (64 B = one row) is read exactly once, by the owning partition.
// ---------------------------------------------------------------------------
__global__ __launch_bounds__(256) void csr_fill_kernel(
    const int* __restrict__ ei, const int* __restrict__ offsets,
    int* __restrict__ cursor, int* __restrict__ csr_src,
    const float* __restrict__ ea, unsigned short* __restrict__ ea_perm) {
  int part = blockIdx.x & 7;
  int e0 = (blockIdx.x >> 3) * 1024 + threadIdx.x * 4;
  if (e0 >= NE) return;
  int4 s4 = *(const int4*)&ei[e0];
  int4 d4 = *(const int4*)&ei[NE + e0];
#pragma unroll
  for (int j = 0; j < 4; ++j) {
    int dst = (&d4.x)[j];
    if ((int)(((long long)dst * 8) / NN) == part) {
      int pos = atomicAdd(&cursor[dst], 1);
      int slot = offsets[dst] + pos;
      csr_src[slot] = (&s4.x)[j];
      const float4* er = (const float4*)(ea + (size_t)(e0 + j) * ED);
      float4 f0 = er[0], f1 = er[1], f2 = er[2], f3 = er[3];
      uint4 o0, o1;
      o0.x = pk2(f0.x, f0.y); o0.y = pk2(f0.z, f0.w);
      o0.z = pk2(f1.x, f1.y); o0.w = pk2(f1.z, f1.w);
      o1.x = pk2(f2.x, f2.y); o1.y = pk2(f2.z, f2.w);
      o1.z = pk2(f3.x, f3.y); o1.w = pk2(f3.z, f3.w);
      uint4* op = (uint4*)(ea_perm + (size_t)slot * 16);
      op[0] = o0; op[1] = o1;
    }
  }
}

// ---------------------------------------------------------------------------
// A[:,128:160] = [ sum_{CSR range} ea_perm (16) | deg | 1.0 | zeros(14) ]
// pure streaming read; 8 lanes per node, 2 cols (one uint) per lane
// ---------------------------------------------------------------------------
__global__ __launch_bounds__(256) void edge_static_kernel(
    const int* __restrict__ offsets, const unsigned short* __restrict__ ea_perm,
    bf16* __restrict__ A) {
  int t = threadIdx.x;
  int node = blockIdx.x * 32 + (t >> 3);
  if (node >= NN) return;
  int k = t & 7;            // cols 2k, 2k+1
  int s = offsets[node], e = offsets[node + 1];
  const unsigned int* ep = (const unsigned int*)ea_perm;
  float a0 = 0.f, a1 = 0.f;
  int p = s;
  for (; p + 2 <= e; p += 2) {
    unsigned int u0 = ep[(size_t)p * 8 + k];
    unsigned int u1 = ep[(size_t)(p + 1) * 8 + k];
    a0 += bf2f((unsigned short)(u0 & 0xffff)) + bf2f((unsigned short)(u1 & 0xffff));
    a1 += bf2f((unsigned short)(u0 >> 16)) + bf2f((unsigned short)(u1 >> 16));
  }
  if (p < e) {
    unsigned int u0 = ep[(size_t)p * 8 + k];
    a0 += bf2f((unsigned short)(u0 & 0xffff));
    a1 += bf2f((unsigned short)(u0 >> 16));
  }
  unsigned short* Au = (unsigned short*)A;
  ((unsigned int*)(Au + (size_t)node * KP + 128))[k] = pk2(a0, a1);
  unsigned int v2 = (k == 0) ? pk2((float)(e - s), 1.0f) : 0u;
  ((unsigned int*)(Au + (size_t)node * KP + 144))[k] = v2;
}

// ---------------------------------------------------------------------------
// Pack W col-major: Wp[b][c][k] = W[b][k][c]
// ---------------------------------------------------------------------------
__global__ __launch_bounds__(256) void pack_w_kernel(
    const float* __restrict__ msg_w, const float* __restrict__ root_w,
    const float* __restrict__ root_b, const float* __restrict__ msg_b,
    bf16* __restrict__ Wp) {
  int idx = blockIdx.x * 256 + threadIdx.x;   // 3*256*160 exact
  int b = idx / (256 * KP);
  int r = idx % (256 * KP);
  int c = r / KP, k = r % KP;
  float v = 0.f;
  if (c < 128) {
    if (k < 128) v = msg_w[((size_t)b * 144 + k) * 128 + c];
  } else {
    int cc = c - 128;
    if (k < 128)       v = root_w[((size_t)b * 128 + k) * 128 + cc];
    else if (k < 144)  v = msg_w[((size_t)b * 144 + k) * 128 + cc];
    else if (k == 144) v = msg_b[(size_t)b * 128 + cc];
    else if (k == 145) v = root_b[(size_t)b * 128 + cc];
  }
  Wp[idx] = (bf16)v;
}

// ---------------------------------------------------------------------------
// lift: A[:,0:128] = bf16(x @ lift_w + lift_b)
// ---------------------------------------------------------------------------
__global__ __launch_bounds__(256) void lift_kernel(
    const float* __restrict__ x, const float* __restrict__ lw,
    const float* __restrict__ lb, bf16* __restrict__ A) {
  int idx = blockIdx.x * 256 + threadIdx.x;   // NN*128 exact
  int n = idx >> 7, k = idx & 127;
  float acc = lb[k];
  const float* xr = x + (size_t)n * ND;
#pragma unroll
  for (int j = 0; j < ND; ++j) acc = fmaf(xr[j], lw[j * H + k], acc);
  A[(size_t)n * KP + k] = (bf16)acc;
}

// ---------------------------------------------------------------------------
// MFMA GEMM: [NN x 160] @ [160 x 256] -> Hw (bf16) | base (f32, +identity)
// ---------------------------------------------------------------------------
__global__ __launch_bounds__(256, 2) void gemm_mfma_kernel(
    const bf16* __restrict__ A, const bf16* __restrict__ Wp,
    bf16* __restrict__ Hw, float* __restrict__ base) {
  __shared__ bf16 as[64 * LDA];
  int t = threadIdx.x;
  int lane = t & 63;
  int wv = t >> 6;
  int l15 = lane & 15, g = lane >> 4;
  int c0w = wv * 64;

  bf16x8 bq[5][4];
#pragma unroll
  for (int kk = 0; kk < 5; ++kk)
#pragma unroll
    for (int ni = 0; ni < 4; ++ni)
      bq[kk][ni] = *(const bf16x8*)(Wp + (size_t)(c0w + ni * 16 + l15) * KP + kk * 32 + g * 8);

  int m0 = blockIdx.x * 64;
#pragma unroll
  for (int i = 0; i < 5; ++i) {
    int idx = i * 256 + t;
    int r = idx / 20, seg = idx % 20;
    int node = m0 + r;
    float4 v = make_float4(0.f, 0.f, 0.f, 0.f);
    if (node < NN) v = *(const float4*)(A + (size_t)node * KP + seg * 8);
    *(float4*)(as + r * LDA + seg * 8) = v;
  }
  __syncthreads();

  f32x4 acc[4][4];
#pragma unroll
  for (int mi = 0; mi < 4; ++mi)
#pragma unroll
    for (int ni = 0; ni < 4; ++ni)
      acc[mi][ni] = (f32x4){0.f, 0.f, 0.f, 0.f};

#pragma unroll
  for (int kk = 0; kk < 5; ++kk) {
    bf16x8 af[4];
#pragma unroll
    for (int mi = 0; mi < 4; ++mi)
      af[mi] = *(const bf16x8*)(as + (mi * 16 + l15) * LDA + kk * 32 + g * 8);
#pragma unroll
    for (int mi = 0; mi < 4; ++mi)
#pragma unroll
      for (int ni = 0; ni < 4; ++ni)
        acc[mi][ni] = __builtin_amdgcn_mfma_f32_16x16x32_bf16(
            af[mi], bq[kk][ni], acc[mi][ni], 0, 0, 0);
  }

#pragma unroll
  for (int mi = 0; mi < 4; ++mi) {
#pragma unroll
    for (int ni = 0; ni < 4; ++ni) {
#pragma unroll
      for (int i = 0; i < 4; ++i) {
        int rloc = mi * 16 + g * 4 + i;
        int row = m0 + rloc;
        int col = c0w + ni * 16 + l15;
        if (row < NN) {
          float v = acc[mi][ni][i];
          if (wv < 2) {
            Hw[(size_t)row * H + col] = (bf16)v;
          } else {
            int cc = col - 128;
            v += bf2f(__builtin_bit_cast(unsigned short, as[rloc * LDA + cc]));
            base[(size_t)row * H + cc] = v;
          }
        }
      }
    }
  }
}

// ---------------------------------------------------------------------------
// h_next = act( base + sum_{e->i} Hw[src[e]] )
//   act==1: write bf16 h into A[:,0:128]
//   act==0 (last block): fuse projection, write out[node][0:4]
// 16 lanes x 16B per node; 16 nodes per 256-thread block; unroll-4
// ---------------------------------------------------------------------------
__global__ __launch_bounds__(256) void gather_update_kernel(
    const int* __restrict__ offsets, const int* __restrict__ csr_src,
    const bf16* __restrict__ Hw, const float* __restrict__ base,
    bf16* __restrict__ A, const float* __restrict__ pw,
    const float* __restrict__ pb, float* __restrict__ out, int act) {
  int t = threadIdx.x;
  int node = blockIdx.x * 16 + (t >> 4);   // NN/16 exact
  int li = t & 15;
  int k8 = li * 8;
  int s = offsets[node], e = offsets[node + 1];
  const unsigned short* Hu = (const unsigned short*)Hw;

  float acc[8];
  {
    float4 b0 = *(const float4*)&base[(size_t)node * H + k8];
    float4 b1 = *(const float4*)&base[(size_t)node * H + k8 + 4];
    acc[0] = b0.x; acc[1] = b0.y; acc[2] = b0.z; acc[3] = b0.w;
    acc[4] = b1.x; acc[5] = b1.y; acc[6] = b1.z; acc[7] = b1.w;
  }

  int p = s;
  for (; p + 4 <= e; p += 4) {
    int s0 = csr_src[p];
    int s1 = csr_src[p + 1];
    int s2 = csr_src[p + 2];
    int s3 = csr_src[p + 3];
    uint4 v0 = *(const uint4*)&Hu[(size_t)s0 * H + k8];
    uint4 v1 = *(const uint4*)&Hu[(size_t)s1 * H + k8];
    uint4 v2 = *(const uint4*)&Hu[(size_t)s2 * H + k8];
    uint4 v3 = *(const uint4*)&Hu[(size_t)s3 * H + k8];
#pragma unroll
    for (int j = 0; j < 4; ++j) {
      unsigned int w0 = (&v0.x)[j], w1 = (&v1.x)[j], w2 = (&v2.x)[j], w3 = (&v3.x)[j];
      acc[2 * j]     += (bf2f((unsigned short)(w0 & 0xffff)) + bf2f((unsigned short)(w1 & 0xffff)))
                      + (bf2f((unsigned short)(w2 & 0xffff)) + bf2f((unsigned short)(w3 & 0xffff)));
      acc[2 * j + 1] += (bf2f((unsigned short)(w0 >> 16)) + bf2f((unsigned short)(w1 >> 16)))
                      + (bf2f((unsigned short)(w2 >> 16)) + bf2f((unsigned short)(w3 >> 16)));
    }
  }
  for (; p < e; ++p) {
    int s0 = csr_src[p];
    uint4 v0 = *(const uint4*)&Hu[(size_t)s0 * H + k8];
#pragma unroll
    for (int j = 0; j < 4; ++j) {
      unsigned int w0 = (&v0.x)[j];
      acc[2 * j]     += bf2f((unsigned short)(w0 & 0xffff));
      acc[2 * j + 1] += bf2f((unsigned short)(w0 >> 16));
    }
  }

  if (act) {
#pragma unroll
    for (int j = 0; j < 8; ++j) {
      float v = acc[j];
      float u = 0.7978845608028654f * (v + 0.044715f * v * v * v);
      acc[j] = 0.5f * v * (1.f + tanhf(u));
    }
    uint4 o;
    o.x = pk2(acc[0], acc[1]);
    o.y = pk2(acc[2], acc[3]);
    o.z = pk2(acc[4], acc[5]);
    o.w = pk2(acc[6], acc[7]);
    *(uint4*)&((unsigned short*)A)[(size_t)node * KP + k8] = o;
  } else {
    float o0 = 0.f, o1 = 0.f, o2 = 0.f, o3 = 0.f;
#pragma unroll
    for (int j = 0; j < 8; ++j) {
      float hv = acc[j];
      const float* pr = pw + (size_t)(k8 + j) * OD;
      o0 = fmaf(hv, pr[0], o0);
      o1 = fmaf(hv, pr[1], o1);
      o2 = fmaf(hv, pr[2], o2);
      o3 = fmaf(hv, pr[3], o3);
    }
#pragma unroll
    for (int m = 8; m >= 1; m >>= 1) {
      o0 += __shfl_xor(o0, m, 16);
      o1 += __shfl_xor(o1, m, 16);
      o2 += __shfl_xor(o2, m, 16);
      o3 += __shfl_xor(o3, m, 16);
    }
    if (li == 0) {
      float4 ov = make_float4(o0 + pb[0], o1 + pb[1], o2 + pb[2], o3 + pb[3]);
      *(float4*)&out[(size_t)node * OD] = ov;
    }
  }
}

extern "C" void kernel_launch(void* const* d_in, const int* in_sizes, int n_in,
                              void* d_out, int out_size, void* d_ws, size_t ws_size,
                              hipStream_t stream) {
  const float* x       = (const float*)d_in[0];
  const int*   ei      = (const int*)d_in[1];
  const float* ea      = (const float*)d_in[2];
  const float* lift_w  = (const float*)d_in[3];
  const float* lift_b  = (const float*)d_in[4];
  const float* root_w  = (const float*)d_in[5];
  const float* root_b  = (const float*)d_in[6];
  const float* msg_w   = (const float*)d_in[7];
  const float* msg_b   = (const float*)d_in[8];
  const float* proj_w  = (const float*)d_in[9];
  const float* proj_b  = (const float*)d_in[10];
  float* out = (float*)d_out;

  char* w = (char*)d_ws;
  bf16*  A      = (bf16*)w;              w += (size_t)NN * KP * 2;       // 16.0 MB
  bf16*  Hw     = (bf16*)w;              w += (size_t)NN * H * 2;        // 12.8 MB
  float* base   = (float*)w;             w += (size_t)NN * H * 4;        // 25.6 MB
  bf16*  Wp     = (bf16*)w;              w += (size_t)3 * 256 * KP * 2;  // 0.25 MB
  int*   csr_src = (int*)w;              w += (size_t)NE * 4;            // 3.2 MB
  unsigned short* ea_perm = (unsigned short*)w;
                                         w += (size_t)NE * 16 * 2;       // 25.6 MB
  int*   deg     = (int*)w;              w += (size_t)NN * 4;
  int*   cursor  = (int*)w;              w += (size_t)NN * 4;
  int*   offsets = (int*)w;              w += (size_t)(NN + 16) * 4;
  int*   tops    = (int*)w;

  const int ntiles = (NN + SCAN_T - 1) / SCAN_T;  // 98

  zero_kernel<<<(NN + 255) / 256, 256, 0, stream>>>(deg, cursor);
  degcount_kernel<<<(NE / 4 + 255) / 256, 256, 0, stream>>>(ei, deg);
  scan_part_kernel<<<ntiles, SCAN_T, 0, stream>>>(deg, offsets, tops);
  scan_tops_kernel<<<1, 64, 0, stream>>>(tops, ntiles, offsets);
  scan_add_kernel<<<(NN + 255) / 256, 256, 0, stream>>>(offsets, tops);
  csr_fill_kernel<<<8 * ((NE + 1023) / 1024), 256, 0, stream>>>(
      ei, offsets, cursor, csr_src, ea, ea_perm);

  edge_static_kernel<<<(NN + 31) / 32, 256, 0, stream>>>(offsets, ea_perm, A);
  pack_w_kernel<<<(3 * 256 * KP) / 256, 256, 0, stream>>>(msg_w, root_w, root_b, msg_b, Wp);
  lift_kernel<<<(NN * H) / 256, 256, 0, stream>>>(x, lift_w, lift_b, A);

  for (int b = 0; b < 3; ++b) {
    gemm_mfma_kernel<<<(NN + 63) / 64, 256, 0, stream>>>(
        A, Wp + (size_t)b * 256 * KP, Hw, base);
    gather_update_kernel<<<NN / 16, 256, 0, stream>>>(
        offsets, csr_src, Hw, base, A, proj_w, proj_b, out, b < 2 ? 1 : 0);
  }
}